// Round 13
// baseline (1947.579 us; speedup 1.0000x reference)
//
#include <hip/hip_runtime.h>
#include <cstdint>
#include <cstddef>

#define HWSZ 65536  // 256*256

__device__ __forceinline__ uint32_t f2bfu(float f) {
  union { float f; uint32_t u; } v; v.f = f;
  return (v.u + 0x7FFFu + ((v.u >> 16) & 1u)) >> 16;  // RNE bf16, as uint
}
__device__ __forceinline__ float bfhi(uint32_t u) {  // high bf16 of pair
  union { uint32_t u; float f; } v; v.u = u & 0xffff0000u;
  return v.f;
}
__device__ __forceinline__ float bflo(uint32_t u) {  // low bf16 of pair
  union { uint32_t u; float f; } v; v.u = u << 16;
  return v.f;
}

// branch-free GELU: A&S 7.1.26 erf (|err| <= 1.5e-7) + v_rcp + v_exp.
// Replaces libm erff (~40-60 ops, multi-path) with ~15 straight-line ops.
__device__ __forceinline__ float gelu_f(float s) {
  const float RS2 = 0.70710678118654752f;
  float z = s * RS2;
  float az = fabsf(z);
  float t = __builtin_amdgcn_rcpf(fmaf(0.3275911f, az, 1.f));
  float poly = t * fmaf(t, fmaf(t, fmaf(t, fmaf(t, 1.061405429f,
                  -1.453152027f), 1.421413741f), -0.284496736f),
                  0.254829592f);
  float e = __builtin_amdgcn_exp2f(z * z * -1.4426950408889634f);
  float erfa = fmaf(-poly, e, 1.f);   // erf(|z|)
  float erfz = copysignf(erfa, z);
  return 0.5f * s * (1.f + erfz);
}

// ---------------- K0: spatial kernel from rfft2 filter --------------------
__global__ void k_prep(const float* __restrict__ F, float* __restrict__ Ks) {
  __shared__ float ct[8];
  int t = threadIdx.x;
  int c = blockIdx.x;
  if (t == 0) {
    const float r2 = 0.70710678118654752f;
    ct[0] = 1.f; ct[1] = r2; ct[2] = 0.f; ct[3] = -r2;
    ct[4] = -1.f; ct[5] = -r2; ct[6] = 0.f; ct[7] = r2;
  }
  __syncthreads();
  int p = t >> 3, q = t & 7;
  const float* Fc = F + c * 40;
  float s = 0.f;
#pragma unroll
  for (int u = 0; u < 8; ++u) {
#pragma unroll
    for (int v = 0; v < 8; ++v) {
      float g = (v <= 4) ? Fc[u * 5 + v] : Fc[((8 - u) & 7) * 5 + (8 - v)];
      s += g * ct[(u * p + v * q) & 7];
    }
  }
  Ks[c * 64 + t] = s * (1.f / 64.f);
}

// ---------------- K0b: transpose w_out [64][256] -> wT [256][64] ----------
__global__ void k_wt(const float* __restrict__ w_out, float* __restrict__ wT) {
  int c = blockIdx.x;   // 256
  int d = threadIdx.x;  // 64
  wT[c * 64 + d] = w_out[d * 256 + c];
}

// ---------------- K0c: pack w_dw 49 -> 64-stride (8-aligned taps) ---------
__global__ void k_wdw(const float* __restrict__ w_dw,
                      const float* __restrict__ b_dw,
                      float* __restrict__ wdwp) {
  int c = blockIdx.x;   // 256
  int t = threadIdx.x;  // 64
  int u = t >> 3, k = t & 7;
  float v = 0.f;
  if (t == 55) v = b_dw[c];
  else if (t < 56 && k < 7) v = w_dw[c * 49 + u * 7 + k];
  wdwp[c * 64 + t] = v;
}

// circular 8x8 conv for one channel: reads bf16-pair row prb[34], kernel kc,
// produces this thread's 4 rows (h*4..h*4+3) packed bf16 into ou[16].
__device__ __forceinline__ void circ8(const uint32_t* __restrict__ prb,
                                      const float* __restrict__ kc, int h,
                                      uint32_t* __restrict__ ou) {
  float o[32];
#pragma unroll
  for (int t = 0; t < 32; ++t) o[t] = 0.f;
#pragma unroll 1
  for (int tph = 0; tph < 2; ++tph) {
    float kh[32];
#pragma unroll
    for (int q4 = 0; q4 < 8; ++q4) {
      float4 kv = *(const float4*)(kc + tph * 32 + q4 * 4);
      kh[q4 * 4 + 0] = kv.x; kh[q4 * 4 + 1] = kv.y;
      kh[q4 * 4 + 2] = kv.z; kh[q4 * 4 + 3] = kv.w;
    }
#pragma unroll
    for (int ii = 0; ii < 4; ++ii) {
      int i = h * 4 + ii;
#pragma unroll
      for (int t4 = 0; t4 < 4; ++t4) {
        int tp = tph * 4 + t4;
        int r = (i - tp) & 7;
        uint2 ua = *(const uint2*)(prb + r * 4);
        uint2 ub = *(const uint2*)(prb + r * 4 + 2);
        float pr[8] = {bflo(ua.x), bfhi(ua.x), bflo(ua.y), bfhi(ua.y),
                       bflo(ub.x), bfhi(ub.x), bflo(ub.y), bfhi(ub.y)};
#pragma unroll
        for (int tq = 0; tq < 8; ++tq) {
          float kv = kh[t4 * 8 + tq];
#pragma unroll
          for (int j = 0; j < 8; ++j)
            o[ii * 8 + j] += kv * pr[(j - tq) & 7];
        }
      }
    }
  }
#pragma unroll
  for (int ii = 0; ii < 4; ++ii) {
    ou[ii * 4 + 0] = f2bfu(o[ii * 8 + 0]) | (f2bfu(o[ii * 8 + 1]) << 16);
    ou[ii * 4 + 1] = f2bfu(o[ii * 8 + 2]) | (f2bfu(o[ii * 8 + 3]) << 16);
    ou[ii * 4 + 2] = f2bfu(o[ii * 8 + 4]) | (f2bfu(o[ii * 8 + 5]) << 16);
    ou[ii * 4 + 3] = f2bfu(o[ii * 8 + 6]) | (f2bfu(o[ii * 8 + 7]) << 16);
  }
}

// ---------------- K1 v8: conv_in 1x1 + bias + patch circular conv ---------
// Pair-split; (256,2) -> allocator budget 128, demand ~95-110 -> no spill.
// (unchanged since R7 — verified: no scratch traffic, ~440-510us)
__global__ __launch_bounds__(256, 2) void k_front(
    const float* __restrict__ x, const float* __restrict__ w_in,
    const float* __restrict__ b_in, const float* __restrict__ Ks,
    uint32_t* __restrict__ midu) {
  __shared__ __align__(16) uint32_t Au[128 * 34];  // x floats, then ch 0-127
  __shared__ __align__(16) uint32_t Bu[128 * 34];  // ch 128-255
  float* xs = (float*)Au;  // 4096 floats during phases 1-2
  int tid = threadIdx.x;
  int orig = blockIdx.x;
  int pid = (orig & 7) * 1024 + (orig >> 3);  // XCD swizzle (8192 % 8 == 0)
  int b = pid >> 10;
  int pp = pid & 1023;
  int ph = pp >> 5, pw = pp & 31;

  // phase 1: stage x patch (4096 floats) cooperatively, coalesced float4
  {
    const float* xb = x + (size_t)b * 64 * HWSZ + (ph * 8) * 256 + pw * 8;
#pragma unroll
    for (int k = 0; k < 4; ++k) {
      int s = tid + k * 256;
      int d = s >> 4, i = (s >> 1) & 7, jh = s & 1;
      float4 v = *(const float4*)(xb + (size_t)d * HWSZ + i * 256 + jh * 4);
      *(float4*)(xs + d * 64 + i * 8 + jh * 4) = v;
    }
  }
  int h = tid & 1;    // pixel-half: rows h*4..h*4+3
  int cp = tid >> 1;  // 0..127
  int c0 = cp, c1 = cp + 128;
  float p0[32], p1[32];
  {
    float bi0 = b_in[c0], bi1 = b_in[c1];
#pragma unroll
    for (int t = 0; t < 32; ++t) { p0[t] = bi0; p1[t] = bi1; }
  }
  __syncthreads();

  // phase 2: conv_in, both channels, my 32 pixels (1 xs read -> 8 FMA)
  const float* w0 = w_in + c0 * 64;
  const float* w1 = w_in + c1 * 64;
#pragma unroll 1
  for (int d8 = 0; d8 < 8; ++d8) {
    float4 wa0 = *(const float4*)(w0 + d8 * 8);
    float4 wb0 = *(const float4*)(w0 + d8 * 8 + 4);
    float4 wa1 = *(const float4*)(w1 + d8 * 8);
    float4 wb1 = *(const float4*)(w1 + d8 * 8 + 4);
    float wv0[8] = {wa0.x, wa0.y, wa0.z, wa0.w, wb0.x, wb0.y, wb0.z, wb0.w};
    float wv1[8] = {wa1.x, wa1.y, wa1.z, wa1.w, wb1.x, wb1.y, wb1.z, wb1.w};
#pragma unroll
    for (int dd = 0; dd < 8; ++dd) {
      const float4* xr = (const float4*)(xs + (d8 * 8 + dd) * 64 + h * 32);
#pragma unroll
      for (int t4 = 0; t4 < 8; ++t4) {
        float4 xv = xr[t4];
        p0[t4 * 4 + 0] += wv0[dd] * xv.x; p1[t4 * 4 + 0] += wv1[dd] * xv.x;
        p0[t4 * 4 + 1] += wv0[dd] * xv.y; p1[t4 * 4 + 1] += wv1[dd] * xv.y;
        p0[t4 * 4 + 2] += wv0[dd] * xv.z; p1[t4 * 4 + 2] += wv1[dd] * xv.z;
        p0[t4 * 4 + 3] += wv0[dd] * xv.w; p1[t4 * 4 + 3] += wv1[dd] * xv.w;
      }
    }
  }
  __syncthreads();  // all conv_in reads of xs done before bf16 overwrite

  // phase 3: pack p -> bf16 pairs, stage c0 -> Au (over xs), c1 -> Bu
  {
    uint32_t* r0 = Au + c0 * 34 + h * 16;
    uint32_t* r1 = Bu + cp * 34 + h * 16;
#pragma unroll
    for (int ii = 0; ii < 4; ++ii) {
      uint2 ua, ub;
      ua.x = f2bfu(p0[ii * 8 + 0]) | (f2bfu(p0[ii * 8 + 1]) << 16);
      ua.y = f2bfu(p0[ii * 8 + 2]) | (f2bfu(p0[ii * 8 + 3]) << 16);
      ub.x = f2bfu(p0[ii * 8 + 4]) | (f2bfu(p0[ii * 8 + 5]) << 16);
      ub.y = f2bfu(p0[ii * 8 + 6]) | (f2bfu(p0[ii * 8 + 7]) << 16);
      *(uint2*)(r0 + ii * 4) = ua;
      *(uint2*)(r0 + ii * 4 + 2) = ub;
      ua.x = f2bfu(p1[ii * 8 + 0]) | (f2bfu(p1[ii * 8 + 1]) << 16);
      ua.y = f2bfu(p1[ii * 8 + 2]) | (f2bfu(p1[ii * 8 + 3]) << 16);
      ub.x = f2bfu(p1[ii * 8 + 4]) | (f2bfu(p1[ii * 8 + 5]) << 16);
      ub.y = f2bfu(p1[ii * 8 + 6]) | (f2bfu(p1[ii * 8 + 7]) << 16);
      *(uint2*)(r1 + ii * 4) = ua;
      *(uint2*)(r1 + ii * 4 + 2) = ub;
    }
  }
  __syncthreads();  // pair's p rows visible before circ conv

  // phase 4a: circ conv ch0 (Au); write back right after the Au-read barrier
  uint32_t ou[16];
  circ8(Au + c0 * 34, Ks + c0 * 64, h, ou);
  __syncthreads();  // both pair-halves finished reading Au row
  {
    uint32_t* r0 = Au + c0 * 34 + h * 16;
#pragma unroll
    for (int m = 0; m < 4; ++m) {
      uint2 ua; ua.x = ou[m * 4 + 0]; ua.y = ou[m * 4 + 1];
      uint2 ub; ub.x = ou[m * 4 + 2]; ub.y = ou[m * 4 + 3];
      *(uint2*)(r0 + m * 4) = ua;
      *(uint2*)(r0 + m * 4 + 2) = ub;
    }
  }
  // phase 4b: circ conv ch1 (Bu; disjoint from the Au writes above)
  circ8(Bu + cp * 34, Ks + c1 * 64, h, ou);
  __syncthreads();  // both pair-halves finished reading Bu row
  {
    uint32_t* r1 = Bu + cp * 34 + h * 16;
#pragma unroll
    for (int m = 0; m < 4; ++m) {
      uint2 ua; ua.x = ou[m * 4 + 0]; ua.y = ou[m * 4 + 1];
      uint2 ub; ub.x = ou[m * 4 + 2]; ub.y = ou[m * 4 + 3];
      *(uint2*)(r1 + m * 4) = ua;
      *(uint2*)(r1 + m * 4 + 2) = ub;
    }
  }
  __syncthreads();

  // phase 6: cooperative fully-coalesced write: 8192 uints (32 KB) / block
  uint32_t* gbase = midu + (size_t)(b * 1024 + pp) * 8192;
#pragma unroll
  for (int k = 0; k < 8; ++k) {
    int g = tid * 4 + k * 1024;
    int w = g & 31;
    uint2 a, e;
    if (k < 4) {  // channels 0..127 live in Au (uniform branch: k static)
      int cc = g >> 5;
      a = *(uint2*)(Au + cc * 34 + w);
      e = *(uint2*)(Au + cc * 34 + w + 2);
    } else {      // channels 128..255 in Bu
      int cc = (g >> 5) - 128;
      a = *(uint2*)(Bu + cc * 34 + w);
      e = *(uint2*)(Bu + cc * 34 + w + 2);
    }
    uint4 q; q.x = a.x; q.y = a.y; q.z = e.x; q.w = e.y;
    *(uint4*)(gbase + g) = q;
  }
}

// ---------------- K2 v10: dw7x7 + bias + GELU + conv_out 1x1 + bias -------
// = R10's proven structure (976us: scalar FMA conv_out, float4 wbuf
// broadcasts, DMA weight staging) + two targeted fixes:
//  (a) TUB 20 -> 48: stride ≡ 16 (mod 32) makes the 4-row x 16-dword read
//      footprint exactly 2 lanes/bank (free, m136). R8-R12 ran 64-81M
//      conflict cycles (~10-15% of kernel) from the stride-20 layout.
//  (b) libm erff (multi-path, ~40-60 ops) -> branch-free A&S 7.1.26 poly
//      (~15 ops, |err|<=1.5e-7 -> GELU err ~1e-5, invisible vs 2e-3).
#define TUB 48
__global__ __launch_bounds__(256, 1) void k_back(
    const uint32_t* __restrict__ midu, const float* __restrict__ wdwp,
    const float* __restrict__ wT, const float* __restrict__ b_out,
    float* __restrict__ out) {
  __shared__ __align__(16) uint32_t tile[2][22 * TUB];  // 8448 B
  __shared__ __align__(16) float wbuf[2][128];  // [0..63]=wdwp, [64..127]=wT
  int t = threadIdx.x;
  int orig = blockIdx.x;
  int pid = (orig & 7) * 128 + (orig >> 3);  // XCD swizzle (1024 % 8 == 0)
  int b = pid >> 7;
  int tb = pid & 127;
  int th = tb >> 3, tw = tb & 7;  // 16 row-tiles x 8 col-tiles
  int R0 = th * 16, C0 = tw * 32;

  // zero-init both tile buffers; out-of-image slots stay zero
  for (int z = t; z < 2 * 22 * TUB; z += 256) ((uint32_t*)tile)[z] = 0u;

  // tile loader lanes: t<176: lr = t>>3 (row 0..21), p = t&7 (quad idx)
  int lr = t >> 3, p = t & 7;
  int g = R0 - 3 + lr;          // global px row
  int pc = 4 * tw - 1 + p;      // global patch col of own quad
  bool aw = (t < 176) && (p < 6) && ((unsigned)g < 256u);  // writer lane
  bool qv = aw && ((unsigned)pc < 32u);                    // own quad valid
  size_t src0 = 0;
  if (qv)
    src0 = ((size_t)(b * 1024 + (g >> 3) * 32 + pc) * 8192) +
           (size_t)((g & 7) * 4);

  int ty = t >> 4, tx = t & 15;
  int lane = t - 192;  // wave-3 lane id (valid when t >= 192)

  float2 acc[64];
#pragma unroll
  for (int d = 0; d < 64; ++d) { acc[d].x = 0.f; acc[d].y = 0.f; }

  __syncthreads();  // zero-init complete before prologue stores

  // prologue: stage channel 0 (tile by t<176; weights DMA'd by wave 3)
  {
    uint4 q; q.x = 0u; q.y = 0u; q.z = 0u; q.w = 0u;
    if (qv) q = *(const uint4*)(midu + src0);
    uint32_t ex = (uint32_t)__shfl_down((int)q.x, 1);  // neighbor quad word0
    if (aw) {
      uint32_t* dr = &tile[0][0] + lr * TUB;
      uint32_t w0 = (q.x >> 16) | (q.y << 16);  // k = 4p-2
      uint32_t w1 = (q.y >> 16) | (q.z << 16);  // k = 4p-1
      uint32_t w2 = (q.z >> 16) | (q.w << 16);  // k = 4p
      uint32_t w3 = (q.w >> 16) | (ex << 16);   // k = 4p+1
      if (p == 0) {
        uint2 hb; hb.x = w2; hb.y = w3;   // k = 0,1
        *(uint2*)(dr + 0) = hb;
      } else if (p == 5) {
        dr[18] = w0;                      // k = 18
      } else {
        uint2 ha; ha.x = w0; ha.y = w1;
        uint2 hb; hb.x = w2; hb.y = w3;
        *(uint2*)(dr + 4 * p - 2) = ha;   // k = 4p-2, 4p-1
        *(uint2*)(dr + 4 * p) = hb;       // k = 4p,   4p+1
      }
    }
    if (t >= 192) {  // wave-uniform: whole wave 3
      __builtin_amdgcn_global_load_lds(
          (const __attribute__((address_space(1))) uint32_t*)(wdwp + lane),
          (__attribute__((address_space(3))) uint32_t*)&wbuf[0][0], 4, 0, 0);
      __builtin_amdgcn_global_load_lds(
          (const __attribute__((address_space(1))) uint32_t*)(wT + lane),
          (__attribute__((address_space(3))) uint32_t*)&wbuf[0][64], 4, 0, 0);
    }
  }
  __syncthreads();

  for (int c = 0; c < 256; ++c) {
    int cur = c & 1;
    bool pf = (c < 255);  // uniform
    // tile prefetch for c+1 (registers, as in R8)
    uint4 q; q.x = 0u; q.y = 0u; q.z = 0u; q.w = 0u;
    if (pf && qv) q = *(const uint4*)(midu + src0 + (size_t)(c + 1) * 32);
    // weight prefetch for c+1: zero-VGPR DMA into wbuf[cur^1]
    if (pf && t >= 192) {
      const float* wds = wdwp + (size_t)(c + 1) * 64 + lane;
      const float* wts = wT + (size_t)(c + 1) * 64 + lane;
      __builtin_amdgcn_global_load_lds(
          (const __attribute__((address_space(1))) uint32_t*)wds,
          (__attribute__((address_space(3))) uint32_t*)&wbuf[cur ^ 1][0],
          4, 0, 0);
      __builtin_amdgcn_global_load_lds(
          (const __attribute__((address_space(1))) uint32_t*)wts,
          (__attribute__((address_space(3))) uint32_t*)&wbuf[cur ^ 1][64],
          4, 0, 0);
    }

    const uint32_t* tl = &tile[cur][0];
    const float* wl = wbuf[cur];
    float s0 = wl[55], s1 = s0;  // bias (broadcast ds_read)
#pragma unroll
    for (int u = 0; u < 7; ++u) {
      const uint32_t* row = tl + (ty + u) * TUB + tx;
      uint32_t k0 = row[0], k1 = row[1], k2 = row[2], k3 = row[3];
      float f0 = bflo(k0), f1 = bfhi(k0), f2 = bflo(k1), f3 = bfhi(k1);
      float f4 = bflo(k2), f5 = bfhi(k2), f6 = bflo(k3), f7 = bfhi(k3);
      float4 wA = *(const float4*)(wl + u * 8);      // taps 0-3 (broadcast)
      float4 wB = *(const float4*)(wl + u * 8 + 4);  // taps 4-6 + pad
      s0 += wA.x * f0 + wA.y * f1 + wA.z * f2 + wA.w * f3 + wB.x * f4 +
            wB.y * f5 + wB.z * f6;
      s1 += wA.x * f1 + wA.y * f2 + wA.z * f3 + wA.w * f4 + wB.x * f5 +
            wB.y * f6 + wB.z * f7;
    }
    float g0 = gelu_f(s0);
    float g1 = gelu_f(s1);

    const float* wcl = wl + 64;
#pragma unroll
    for (int d4 = 0; d4 < 16; ++d4) {
      float4 wv = *(const float4*)(wcl + d4 * 4);  // broadcast ds_read_b128
      acc[d4 * 4 + 0].x += g0 * wv.x; acc[d4 * 4 + 0].y += g1 * wv.x;
      acc[d4 * 4 + 1].x += g0 * wv.y; acc[d4 * 4 + 1].y += g1 * wv.y;
      acc[d4 * 4 + 2].x += g0 * wv.z; acc[d4 * 4 + 2].y += g1 * wv.z;
      acc[d4 * 4 + 3].x += g0 * wv.w; acc[d4 * 4 + 3].y += g1 * wv.w;
    }

    if (pf) {
      uint32_t ex = (uint32_t)__shfl_down((int)q.x, 1);
      if (aw) {
        uint32_t* dr = &tile[cur ^ 1][0] + lr * TUB;
        uint32_t w0 = (q.x >> 16) | (q.y << 16);
        uint32_t w1 = (q.y >> 16) | (q.z << 16);
        uint32_t w2 = (q.z >> 16) | (q.w << 16);
        uint32_t w3 = (q.w >> 16) | (ex << 16);
        if (p == 0) {
          uint2 hb; hb.x = w2; hb.y = w3;
          *(uint2*)(dr + 0) = hb;
        } else if (p == 5) {
          dr[18] = w0;
        } else {
          uint2 ha; ha.x = w0; ha.y = w1;
          uint2 hb; hb.x = w2; hb.y = w3;
          *(uint2*)(dr + 4 * p - 2) = ha;
          *(uint2*)(dr + 4 * p) = hb;
        }
      }
    }
    __syncthreads();
  }

  // coalesced float2 stores: lanes cover consecutive 8B spans of each row
  size_t obase = (size_t)b * 64 * HWSZ + (size_t)(R0 + ty) * 256 + C0 + 2 * tx;
#pragma unroll
  for (int d = 0; d < 64; ++d) {
    float bo = b_out[d];  // uniform -> s_load
    float2 v; v.x = acc[d].x + bo; v.y = acc[d].y + bo;
    *(float2*)(out + obase + (size_t)d * HWSZ) = v;
  }
}

extern "C" void kernel_launch(void* const* d_in, const int* in_sizes, int n_in,
                              void* d_out, int out_size, void* d_ws, size_t ws_size,
                              hipStream_t stream) {
  (void)in_sizes; (void)n_in; (void)out_size; (void)ws_size;
  const float* x     = (const float*)d_in[0];
  const float* w_in  = (const float*)d_in[1];
  const float* b_in  = (const float*)d_in[2];
  const float* fftf  = (const float*)d_in[3];
  const float* w_dw  = (const float*)d_in[4];
  const float* b_dw  = (const float*)d_in[5];
  const float* w_out = (const float*)d_in[6];
  const float* b_out = (const float*)d_in[7];
  float* out = (float*)d_out;

  float* Ks = (float*)d_ws;                                   // 64 KB
  float* wT = (float*)((char*)d_ws + 65536);                  // 64 KB
  float* wdwp = (float*)((char*)d_ws + 131072);               // 64 KB
  uint32_t* midu = (uint32_t*)((char*)d_ws + 196608);         // 268 MB

  k_prep<<<256, 64, 0, stream>>>(fftf, Ks);
  k_wt<<<256, 64, 0, stream>>>(w_out, wT);
  k_wdw<<<256, 64, 0, stream>>>(w_dw, b_dw, wdwp);
  k_front<<<8192, 256, 0, stream>>>(x, w_in, b_in, Ks, midu);
  k_back<<<1024, 256, 0, stream>>>(midu, wdwp, wT, b_out, out);
}

// Round 14
// 1381.032 us; speedup vs baseline: 1.4102x; 1.4102x over previous
//
#include <hip/hip_runtime.h>
#include <cstdint>
#include <cstddef>

#define HWSZ 65536  // 256*256

__device__ __forceinline__ uint32_t f2bfu(float f) {
  union { float f; uint32_t u; } v; v.f = f;
  return (v.u + 0x7FFFu + ((v.u >> 16) & 1u)) >> 16;  // RNE bf16, as uint
}
__device__ __forceinline__ float bfhi(uint32_t u) {  // high bf16 of pair
  union { uint32_t u; float f; } v; v.u = u & 0xffff0000u;
  return v.f;
}
__device__ __forceinline__ float bflo(uint32_t u) {  // low bf16 of pair
  union { uint32_t u; float f; } v; v.u = u << 16;
  return v.f;
}

// ---------------- K0: spatial kernel from rfft2 filter --------------------
__global__ void k_prep(const float* __restrict__ F, float* __restrict__ Ks) {
  __shared__ float ct[8];
  int t = threadIdx.x;
  int c = blockIdx.x;
  if (t == 0) {
    const float r2 = 0.70710678118654752f;
    ct[0] = 1.f; ct[1] = r2; ct[2] = 0.f; ct[3] = -r2;
    ct[4] = -1.f; ct[5] = -r2; ct[6] = 0.f; ct[7] = r2;
  }
  __syncthreads();
  int p = t >> 3, q = t & 7;
  const float* Fc = F + c * 40;
  float s = 0.f;
#pragma unroll
  for (int u = 0; u < 8; ++u) {
#pragma unroll
    for (int v = 0; v < 8; ++v) {
      float g = (v <= 4) ? Fc[u * 5 + v] : Fc[((8 - u) & 7) * 5 + (8 - v)];
      s += g * ct[(u * p + v * q) & 7];
    }
  }
  Ks[c * 64 + t] = s * (1.f / 64.f);
}

// ---------------- K0b: transpose w_out [64][256] -> wT [256][64] ----------
__global__ void k_wt(const float* __restrict__ w_out, float* __restrict__ wT) {
  int c = blockIdx.x;   // 256
  int d = threadIdx.x;  // 64
  wT[c * 64 + d] = w_out[d * 256 + c];
}

// ---------------- K0c: pack w_dw 49 -> 64-stride (8-aligned taps) ---------
__global__ void k_wdw(const float* __restrict__ w_dw,
                      const float* __restrict__ b_dw,
                      float* __restrict__ wdwp) {
  int c = blockIdx.x;   // 256
  int t = threadIdx.x;  // 64
  int u = t >> 3, k = t & 7;
  float v = 0.f;
  if (t == 55) v = b_dw[c];
  else if (t < 56 && k < 7) v = w_dw[c * 49 + u * 7 + k];
  wdwp[c * 64 + t] = v;
}

// circular 8x8 conv for one channel: reads bf16-pair row prb[34], kernel kc,
// produces this thread's 4 rows (h*4..h*4+3) packed bf16 into ou[16].
__device__ __forceinline__ void circ8(const uint32_t* __restrict__ prb,
                                      const float* __restrict__ kc, int h,
                                      uint32_t* __restrict__ ou) {
  float o[32];
#pragma unroll
  for (int t = 0; t < 32; ++t) o[t] = 0.f;
#pragma unroll 1
  for (int tph = 0; tph < 2; ++tph) {
    float kh[32];
#pragma unroll
    for (int q4 = 0; q4 < 8; ++q4) {
      float4 kv = *(const float4*)(kc + tph * 32 + q4 * 4);
      kh[q4 * 4 + 0] = kv.x; kh[q4 * 4 + 1] = kv.y;
      kh[q4 * 4 + 2] = kv.z; kh[q4 * 4 + 3] = kv.w;
    }
#pragma unroll
    for (int ii = 0; ii < 4; ++ii) {
      int i = h * 4 + ii;
#pragma unroll
      for (int t4 = 0; t4 < 4; ++t4) {
        int tp = tph * 4 + t4;
        int r = (i - tp) & 7;
        uint2 ua = *(const uint2*)(prb + r * 4);
        uint2 ub = *(const uint2*)(prb + r * 4 + 2);
        float pr[8] = {bflo(ua.x), bfhi(ua.x), bflo(ua.y), bfhi(ua.y),
                       bflo(ub.x), bfhi(ub.x), bflo(ub.y), bfhi(ub.y)};
#pragma unroll
        for (int tq = 0; tq < 8; ++tq) {
          float kv = kh[t4 * 8 + tq];
#pragma unroll
          for (int j = 0; j < 8; ++j)
            o[ii * 8 + j] += kv * pr[(j - tq) & 7];
        }
      }
    }
  }
#pragma unroll
  for (int ii = 0; ii < 4; ++ii) {
    ou[ii * 4 + 0] = f2bfu(o[ii * 8 + 0]) | (f2bfu(o[ii * 8 + 1]) << 16);
    ou[ii * 4 + 1] = f2bfu(o[ii * 8 + 2]) | (f2bfu(o[ii * 8 + 3]) << 16);
    ou[ii * 4 + 2] = f2bfu(o[ii * 8 + 4]) | (f2bfu(o[ii * 8 + 5]) << 16);
    ou[ii * 4 + 3] = f2bfu(o[ii * 8 + 6]) | (f2bfu(o[ii * 8 + 7]) << 16);
  }
}

// ---------------- K1 v8: conv_in 1x1 + bias + patch circular conv ---------
// Pair-split; (256,2) -> allocator budget 128, demand ~95-110 -> no spill.
// (unchanged since R7 — verified: no scratch traffic, ~440-510us)
__global__ __launch_bounds__(256, 2) void k_front(
    const float* __restrict__ x, const float* __restrict__ w_in,
    const float* __restrict__ b_in, const float* __restrict__ Ks,
    uint32_t* __restrict__ midu) {
  __shared__ __align__(16) uint32_t Au[128 * 34];  // x floats, then ch 0-127
  __shared__ __align__(16) uint32_t Bu[128 * 34];  // ch 128-255
  float* xs = (float*)Au;  // 4096 floats during phases 1-2
  int tid = threadIdx.x;
  int orig = blockIdx.x;
  int pid = (orig & 7) * 1024 + (orig >> 3);  // XCD swizzle (8192 % 8 == 0)
  int b = pid >> 10;
  int pp = pid & 1023;
  int ph = pp >> 5, pw = pp & 31;

  // phase 1: stage x patch (4096 floats) cooperatively, coalesced float4
  {
    const float* xb = x + (size_t)b * 64 * HWSZ + (ph * 8) * 256 + pw * 8;
#pragma unroll
    for (int k = 0; k < 4; ++k) {
      int s = tid + k * 256;
      int d = s >> 4, i = (s >> 1) & 7, jh = s & 1;
      float4 v = *(const float4*)(xb + (size_t)d * HWSZ + i * 256 + jh * 4);
      *(float4*)(xs + d * 64 + i * 8 + jh * 4) = v;
    }
  }
  int h = tid & 1;    // pixel-half: rows h*4..h*4+3
  int cp = tid >> 1;  // 0..127
  int c0 = cp, c1 = cp + 128;
  float p0[32], p1[32];
  {
    float bi0 = b_in[c0], bi1 = b_in[c1];
#pragma unroll
    for (int t = 0; t < 32; ++t) { p0[t] = bi0; p1[t] = bi1; }
  }
  __syncthreads();

  // phase 2: conv_in, both channels, my 32 pixels (1 xs read -> 8 FMA)
  const float* w0 = w_in + c0 * 64;
  const float* w1 = w_in + c1 * 64;
#pragma unroll 1
  for (int d8 = 0; d8 < 8; ++d8) {
    float4 wa0 = *(const float4*)(w0 + d8 * 8);
    float4 wb0 = *(const float4*)(w0 + d8 * 8 + 4);
    float4 wa1 = *(const float4*)(w1 + d8 * 8);
    float4 wb1 = *(const float4*)(w1 + d8 * 8 + 4);
    float wv0[8] = {wa0.x, wa0.y, wa0.z, wa0.w, wb0.x, wb0.y, wb0.z, wb0.w};
    float wv1[8] = {wa1.x, wa1.y, wa1.z, wa1.w, wb1.x, wb1.y, wb1.z, wb1.w};
#pragma unroll
    for (int dd = 0; dd < 8; ++dd) {
      const float4* xr = (const float4*)(xs + (d8 * 8 + dd) * 64 + h * 32);
#pragma unroll
      for (int t4 = 0; t4 < 8; ++t4) {
        float4 xv = xr[t4];
        p0[t4 * 4 + 0] += wv0[dd] * xv.x; p1[t4 * 4 + 0] += wv1[dd] * xv.x;
        p0[t4 * 4 + 1] += wv0[dd] * xv.y; p1[t4 * 4 + 1] += wv1[dd] * xv.y;
        p0[t4 * 4 + 2] += wv0[dd] * xv.z; p1[t4 * 4 + 2] += wv1[dd] * xv.z;
        p0[t4 * 4 + 3] += wv0[dd] * xv.w; p1[t4 * 4 + 3] += wv1[dd] * xv.w;
      }
    }
  }
  __syncthreads();  // all conv_in reads of xs done before bf16 overwrite

  // phase 3: pack p -> bf16 pairs, stage c0 -> Au (over xs), c1 -> Bu
  {
    uint32_t* r0 = Au + c0 * 34 + h * 16;
    uint32_t* r1 = Bu + cp * 34 + h * 16;
#pragma unroll
    for (int ii = 0; ii < 4; ++ii) {
      uint2 ua, ub;
      ua.x = f2bfu(p0[ii * 8 + 0]) | (f2bfu(p0[ii * 8 + 1]) << 16);
      ua.y = f2bfu(p0[ii * 8 + 2]) | (f2bfu(p0[ii * 8 + 3]) << 16);
      ub.x = f2bfu(p0[ii * 8 + 4]) | (f2bfu(p0[ii * 8 + 5]) << 16);
      ub.y = f2bfu(p0[ii * 8 + 6]) | (f2bfu(p0[ii * 8 + 7]) << 16);
      *(uint2*)(r0 + ii * 4) = ua;
      *(uint2*)(r0 + ii * 4 + 2) = ub;
      ua.x = f2bfu(p1[ii * 8 + 0]) | (f2bfu(p1[ii * 8 + 1]) << 16);
      ua.y = f2bfu(p1[ii * 8 + 2]) | (f2bfu(p1[ii * 8 + 3]) << 16);
      ub.x = f2bfu(p1[ii * 8 + 4]) | (f2bfu(p1[ii * 8 + 5]) << 16);
      ub.y = f2bfu(p1[ii * 8 + 6]) | (f2bfu(p1[ii * 8 + 7]) << 16);
      *(uint2*)(r1 + ii * 4) = ua;
      *(uint2*)(r1 + ii * 4 + 2) = ub;
    }
  }
  __syncthreads();  // pair's p rows visible before circ conv

  // phase 4a: circ conv ch0 (Au); write back right after the Au-read barrier
  uint32_t ou[16];
  circ8(Au + c0 * 34, Ks + c0 * 64, h, ou);
  __syncthreads();  // both pair-halves finished reading Au row
  {
    uint32_t* r0 = Au + c0 * 34 + h * 16;
#pragma unroll
    for (int m = 0; m < 4; ++m) {
      uint2 ua; ua.x = ou[m * 4 + 0]; ua.y = ou[m * 4 + 1];
      uint2 ub; ub.x = ou[m * 4 + 2]; ub.y = ou[m * 4 + 3];
      *(uint2*)(r0 + m * 4) = ua;
      *(uint2*)(r0 + m * 4 + 2) = ub;
    }
  }
  // phase 4b: circ conv ch1 (Bu; disjoint from the Au writes above)
  circ8(Bu + cp * 34, Ks + c1 * 64, h, ou);
  __syncthreads();  // both pair-halves finished reading Bu row
  {
    uint32_t* r1 = Bu + cp * 34 + h * 16;
#pragma unroll
    for (int m = 0; m < 4; ++m) {
      uint2 ua; ua.x = ou[m * 4 + 0]; ua.y = ou[m * 4 + 1];
      uint2 ub; ub.x = ou[m * 4 + 2]; ub.y = ou[m * 4 + 3];
      *(uint2*)(r1 + m * 4) = ua;
      *(uint2*)(r1 + m * 4 + 2) = ub;
    }
  }
  __syncthreads();

  // phase 6: cooperative fully-coalesced write: 8192 uints (32 KB) / block
  uint32_t* gbase = midu + (size_t)(b * 1024 + pp) * 8192;
#pragma unroll
  for (int k = 0; k < 8; ++k) {
    int g = tid * 4 + k * 1024;
    int w = g & 31;
    uint2 a, e;
    if (k < 4) {  // channels 0..127 live in Au (uniform branch: k static)
      int cc = g >> 5;
      a = *(uint2*)(Au + cc * 34 + w);
      e = *(uint2*)(Au + cc * 34 + w + 2);
    } else {      // channels 128..255 in Bu
      int cc = (g >> 5) - 128;
      a = *(uint2*)(Bu + cc * 34 + w);
      e = *(uint2*)(Bu + cc * 34 + w + 2);
    }
    uint4 q; q.x = a.x; q.y = a.y; q.z = e.x; q.w = e.y;
    *(uint4*)(gbase + g) = q;
  }
}

// ---------------- K2 v11: dw7x7 + bias + GELU + conv_out 1x1 + bias -------
// = R10's exact structure (976us: scalar FMA conv_out, float4 wbuf
// broadcasts, DMA weight staging, libm erff) + ONLY the verified fix from
// R13: TUB 20 -> 48 (stride ≡ 16 mod 32 -> 2 lanes/bank, free). R13 proved
// conflicts 81M -> 1.3M; R13's erf-poly is DROPPED (it cost +28 VGPR ->
// 276 > 256 combined -> occupancy halved; erff's tight register footprint
// wins at this kernel's exact-256 budget).
#define TUB 48
__global__ __launch_bounds__(256, 1) void k_back(
    const uint32_t* __restrict__ midu, const float* __restrict__ wdwp,
    const float* __restrict__ wT, const float* __restrict__ b_out,
    float* __restrict__ out) {
  __shared__ __align__(16) uint32_t tile[2][22 * TUB];  // 8448 B
  __shared__ __align__(16) float wbuf[2][128];  // [0..63]=wdwp, [64..127]=wT
  int t = threadIdx.x;
  int orig = blockIdx.x;
  int pid = (orig & 7) * 128 + (orig >> 3);  // XCD swizzle (1024 % 8 == 0)
  int b = pid >> 7;
  int tb = pid & 127;
  int th = tb >> 3, tw = tb & 7;  // 16 row-tiles x 8 col-tiles
  int R0 = th * 16, C0 = tw * 32;

  // zero-init both tile buffers; out-of-image slots stay zero
  for (int z = t; z < 2 * 22 * TUB; z += 256) ((uint32_t*)tile)[z] = 0u;

  // tile loader lanes: t<176: lr = t>>3 (row 0..21), p = t&7 (quad idx)
  int lr = t >> 3, p = t & 7;
  int g = R0 - 3 + lr;          // global px row
  int pc = 4 * tw - 1 + p;      // global patch col of own quad
  bool aw = (t < 176) && (p < 6) && ((unsigned)g < 256u);  // writer lane
  bool qv = aw && ((unsigned)pc < 32u);                    // own quad valid
  size_t src0 = 0;
  if (qv)
    src0 = ((size_t)(b * 1024 + (g >> 3) * 32 + pc) * 8192) +
           (size_t)((g & 7) * 4);

  int ty = t >> 4, tx = t & 15;
  int lane = t - 192;  // wave-3 lane id (valid when t >= 192)

  float2 acc[64];
#pragma unroll
  for (int d = 0; d < 64; ++d) { acc[d].x = 0.f; acc[d].y = 0.f; }

  __syncthreads();  // zero-init complete before prologue stores

  // prologue: stage channel 0 (tile by t<176; weights DMA'd by wave 3)
  {
    uint4 q; q.x = 0u; q.y = 0u; q.z = 0u; q.w = 0u;
    if (qv) q = *(const uint4*)(midu + src0);
    uint32_t ex = (uint32_t)__shfl_down((int)q.x, 1);  // neighbor quad word0
    if (aw) {
      uint32_t* dr = &tile[0][0] + lr * TUB;
      uint32_t w0 = (q.x >> 16) | (q.y << 16);  // k = 4p-2
      uint32_t w1 = (q.y >> 16) | (q.z << 16);  // k = 4p-1
      uint32_t w2 = (q.z >> 16) | (q.w << 16);  // k = 4p
      uint32_t w3 = (q.w >> 16) | (ex << 16);   // k = 4p+1
      if (p == 0) {
        uint2 hb; hb.x = w2; hb.y = w3;   // k = 0,1
        *(uint2*)(dr + 0) = hb;
      } else if (p == 5) {
        dr[18] = w0;                      // k = 18
      } else {
        uint2 ha; ha.x = w0; ha.y = w1;
        uint2 hb; hb.x = w2; hb.y = w3;
        *(uint2*)(dr + 4 * p - 2) = ha;   // k = 4p-2, 4p-1
        *(uint2*)(dr + 4 * p) = hb;       // k = 4p,   4p+1
      }
    }
    if (t >= 192) {  // wave-uniform: whole wave 3
      __builtin_amdgcn_global_load_lds(
          (const __attribute__((address_space(1))) uint32_t*)(wdwp + lane),
          (__attribute__((address_space(3))) uint32_t*)&wbuf[0][0], 4, 0, 0);
      __builtin_amdgcn_global_load_lds(
          (const __attribute__((address_space(1))) uint32_t*)(wT + lane),
          (__attribute__((address_space(3))) uint32_t*)&wbuf[0][64], 4, 0, 0);
    }
  }
  __syncthreads();

  for (int c = 0; c < 256; ++c) {
    int cur = c & 1;
    bool pf = (c < 255);  // uniform
    // tile prefetch for c+1 (registers, as in R8)
    uint4 q; q.x = 0u; q.y = 0u; q.z = 0u; q.w = 0u;
    if (pf && qv) q = *(const uint4*)(midu + src0 + (size_t)(c + 1) * 32);
    // weight prefetch for c+1: zero-VGPR DMA into wbuf[cur^1]
    if (pf && t >= 192) {
      const float* wds = wdwp + (size_t)(c + 1) * 64 + lane;
      const float* wts = wT + (size_t)(c + 1) * 64 + lane;
      __builtin_amdgcn_global_load_lds(
          (const __attribute__((address_space(1))) uint32_t*)wds,
          (__attribute__((address_space(3))) uint32_t*)&wbuf[cur ^ 1][0],
          4, 0, 0);
      __builtin_amdgcn_global_load_lds(
          (const __attribute__((address_space(1))) uint32_t*)wts,
          (__attribute__((address_space(3))) uint32_t*)&wbuf[cur ^ 1][64],
          4, 0, 0);
    }

    const uint32_t* tl = &tile[cur][0];
    const float* wl = wbuf[cur];
    float s0 = wl[55], s1 = s0;  // bias (broadcast ds_read)
#pragma unroll
    for (int u = 0; u < 7; ++u) {
      const uint32_t* row = tl + (ty + u) * TUB + tx;
      uint32_t k0 = row[0], k1 = row[1], k2 = row[2], k3 = row[3];
      float f0 = bflo(k0), f1 = bfhi(k0), f2 = bflo(k1), f3 = bfhi(k1);
      float f4 = bflo(k2), f5 = bfhi(k2), f6 = bflo(k3), f7 = bfhi(k3);
      float4 wA = *(const float4*)(wl + u * 8);      // taps 0-3 (broadcast)
      float4 wB = *(const float4*)(wl + u * 8 + 4);  // taps 4-6 + pad
      s0 += wA.x * f0 + wA.y * f1 + wA.z * f2 + wA.w * f3 + wB.x * f4 +
            wB.y * f5 + wB.z * f6;
      s1 += wA.x * f1 + wA.y * f2 + wA.z * f3 + wA.w * f4 + wB.x * f5 +
            wB.y * f6 + wB.z * f7;
    }
    const float RS2 = 0.70710678118654752f;
    float g0 = 0.5f * s0 * (1.f + erff(s0 * RS2));
    float g1 = 0.5f * s1 * (1.f + erff(s1 * RS2));

    const float* wcl = wl + 64;
#pragma unroll
    for (int d4 = 0; d4 < 16; ++d4) {
      float4 wv = *(const float4*)(wcl + d4 * 4);  // broadcast ds_read_b128
      acc[d4 * 4 + 0].x += g0 * wv.x; acc[d4 * 4 + 0].y += g1 * wv.x;
      acc[d4 * 4 + 1].x += g0 * wv.y; acc[d4 * 4 + 1].y += g1 * wv.y;
      acc[d4 * 4 + 2].x += g0 * wv.z; acc[d4 * 4 + 2].y += g1 * wv.z;
      acc[d4 * 4 + 3].x += g0 * wv.w; acc[d4 * 4 + 3].y += g1 * wv.w;
    }

    if (pf) {
      uint32_t ex = (uint32_t)__shfl_down((int)q.x, 1);
      if (aw) {
        uint32_t* dr = &tile[cur ^ 1][0] + lr * TUB;
        uint32_t w0 = (q.x >> 16) | (q.y << 16);
        uint32_t w1 = (q.y >> 16) | (q.z << 16);
        uint32_t w2 = (q.z >> 16) | (q.w << 16);
        uint32_t w3 = (q.w >> 16) | (ex << 16);
        if (p == 0) {
          uint2 hb; hb.x = w2; hb.y = w3;
          *(uint2*)(dr + 0) = hb;
        } else if (p == 5) {
          dr[18] = w0;
        } else {
          uint2 ha; ha.x = w0; ha.y = w1;
          uint2 hb; hb.x = w2; hb.y = w3;
          *(uint2*)(dr + 4 * p - 2) = ha;
          *(uint2*)(dr + 4 * p) = hb;
        }
      }
    }
    __syncthreads();
  }

  // coalesced float2 stores: lanes cover consecutive 8B spans of each row
  size_t obase = (size_t)b * 64 * HWSZ + (size_t)(R0 + ty) * 256 + C0 + 2 * tx;
#pragma unroll
  for (int d = 0; d < 64; ++d) {
    float bo = b_out[d];  // uniform -> s_load
    float2 v; v.x = acc[d].x + bo; v.y = acc[d].y + bo;
    *(float2*)(out + obase + (size_t)d * HWSZ) = v;
  }
}

extern "C" void kernel_launch(void* const* d_in, const int* in_sizes, int n_in,
                              void* d_out, int out_size, void* d_ws, size_t ws_size,
                              hipStream_t stream) {
  (void)in_sizes; (void)n_in; (void)out_size; (void)ws_size;
  const float* x     = (const float*)d_in[0];
  const float* w_in  = (const float*)d_in[1];
  const float* b_in  = (const float*)d_in[2];
  const float* fftf  = (const float*)d_in[3];
  const float* w_dw  = (const float*)d_in[4];
  const float* b_dw  = (const float*)d_in[5];
  const float* w_out = (const float*)d_in[6];
  const float* b_out = (const float*)d_in[7];
  float* out = (float*)d_out;

  float* Ks = (float*)d_ws;                                   // 64 KB
  float* wT = (float*)((char*)d_ws + 65536);                  // 64 KB
  float* wdwp = (float*)((char*)d_ws + 131072);               // 64 KB
  uint32_t* midu = (uint32_t*)((char*)d_ws + 196608);         // 268 MB

  k_prep<<<256, 64, 0, stream>>>(fftf, Ks);
  k_wt<<<256, 64, 0, stream>>>(w_out, wT);
  k_wdw<<<256, 64, 0, stream>>>(w_dw, b_dw, wdwp);
  k_front<<<8192, 256, 0, stream>>>(x, w_in, b_in, Ks, midu);
  k_back<<<1024, 256, 0, stream>>>(midu, wdwp, wT, b_out, out);
}